// Round 1
// baseline (53.817 us; speedup 1.0000x reference)
//
#include <hip/hip_runtime.h>

// dEMD greedy multi-marginal EMD, D=4 rows, N=2048 bins.
//
// Closed-form reformulation of the sequential greedy loop:
//   Every greedy step subtracts minval from ALL row fronts, so the consumed
//   mass T is identical across rows at all times. Pointer of row i at mass T:
//       idx_i(T) = #{ j in [1..N] : S_i(j) <= T },  S_i = inclusive prefix sum
//   Loop terminates at Tend = min_i S_i(N) (first pointer reaches N).
//   obj = integral over [0,Tend] of (max_i idx_i - min_i idx_i) dT
//       = sum_{m=1..N} (Tend - A_m) - max(0, Tend - B_m)
//   with A_m = min_i S_i(m), B_m = max_i S_i(m)  (level-set decomposition).
// This turns 8189 sequential steps into 4 parallel prefix scans + a reduction.

constexpr int D       = 4;
constexpr int N       = 2048;
constexpr int THREADS = 256;        // 4 waves, one wave per row
constexpr int PER_LANE = N / 64;    // 32 elements per lane

__global__ __launch_bounds__(THREADS)
void demd_kernel(const float* __restrict__ x, float* __restrict__ out) {
    __shared__ float  S[D][N];       // 32 KB: inclusive prefix sums per row
    __shared__ double red[THREADS];  // 2 KB: block reduction

    const int t    = threadIdx.x;
    const int wave = t >> 6;         // row index 0..3
    const int lane = t & 63;

    // ---- phase 1: per-row inclusive prefix sum, one wave per row ----
    {
        const float* row = x + wave * N + lane * PER_LANE;
        float v[PER_LANE];
        #pragma unroll
        for (int k = 0; k < PER_LANE / 4; ++k) {
            float4 f = ((const float4*)row)[k];
            v[4*k+0] = f.x; v[4*k+1] = f.y; v[4*k+2] = f.z; v[4*k+3] = f.w;
        }
        double tot = 0.0;
        #pragma unroll
        for (int k = 0; k < PER_LANE; ++k) tot += (double)v[k];

        // wave-level inclusive scan of lane totals (64 lanes)
        double scan = tot;
        #pragma unroll
        for (int off = 1; off < 64; off <<= 1) {
            double up = __shfl_up(scan, off, 64);
            if (lane >= off) scan += up;
        }
        double run = scan - tot;     // exclusive prefix for this lane
        float* Srow = &S[wave][lane * PER_LANE];
        #pragma unroll
        for (int k = 0; k < PER_LANE; ++k) {
            run += (double)v[k];
            Srow[k] = (float)run;
        }
    }
    __syncthreads();

    // ---- phase 2: obj = sum_m (Tend - A_m) - relu(Tend - B_m) ----
    float tend = S[0][N - 1];
    #pragma unroll
    for (int r = 1; r < D; ++r) tend = fminf(tend, S[r][N - 1]);

    double acc = 0.0;
    #pragma unroll
    for (int k = 0; k < N / THREADS; ++k) {
        const int j = t + k * THREADS;
        float a = S[0][j];
        float b = a;
        #pragma unroll
        for (int r = 1; r < D; ++r) {
            float s = S[r][j];
            a = fminf(a, s);
            b = fmaxf(b, s);
        }
        acc += (double)((tend - a) - fmaxf(0.0f, tend - b));
    }
    red[t] = acc;
    __syncthreads();
    #pragma unroll
    for (int s = THREADS / 2; s > 0; s >>= 1) {
        if (t < s) red[t] += red[t + s];
        __syncthreads();
    }
    if (t == 0) out[0] = (float)red[0];
}

extern "C" void kernel_launch(void* const* d_in, const int* in_sizes, int n_in,
                              void* d_out, int out_size, void* d_ws, size_t ws_size,
                              hipStream_t stream) {
    (void)in_sizes; (void)n_in; (void)d_ws; (void)ws_size; (void)out_size;
    const float* x = (const float*)d_in[0];
    float* out = (float*)d_out;
    demd_kernel<<<1, THREADS, 0, stream>>>(x, out);
}

// Round 2
// 52.974 us; speedup vs baseline: 1.0159x; 1.0159x over previous
//
#include <hip/hip_runtime.h>

// dEMD greedy multi-marginal EMD, D=4 rows, N=2048 bins.
//
// Closed-form reformulation of the sequential greedy loop:
//   Every greedy step subtracts minval from ALL row fronts, so the consumed
//   mass T is identical across rows at all times. Pointer of row i at mass T:
//       idx_i(T) = #{ j in [1..N] : S_i(j) <= T },  S_i = inclusive prefix sum
//   Loop terminates at Tend = min_i S_i(N) (first pointer reaches N).
//   obj = integral over [0,Tend] of (max_i idx_i - min_i idx_i) dT
//       = sum_{m=1..N} (Tend - A_m) - max(0, Tend - B_m)
//   with A_m = min_i S_i(m), B_m = max_i S_i(m)  (level-set decomposition).
//
// R2: single-wave, all-fp32, zero-LDS version. Each lane owns a 32-column
// chunk of ALL FOUR rows in registers; the 4 row-scans run as independent
// dependent-chains (4-way ILP), cross-row min/max is per-lane register math,
// and the final sum is one shuffle reduction. No barriers, no LDS, no f64.
// fp32 scan error ~1e-2 vs threshold 655.36 — precision is free to drop.

constexpr int D        = 4;
constexpr int N        = 2048;
constexpr int PER_LANE = N / 64;    // 32 columns per lane

__global__ __launch_bounds__(64)
void demd_kernel(const float* __restrict__ x, float* __restrict__ out) {
    const int lane = threadIdx.x;

    // ---- load: 4 rows x 32 columns per lane (128 B per row per lane) ----
    float v[D][PER_LANE];
    #pragma unroll
    for (int r = 0; r < D; ++r) {
        const float4* src = (const float4*)(x + r * N + lane * PER_LANE);
        #pragma unroll
        for (int k = 0; k < PER_LANE / 4; ++k) {
            float4 f = src[k];
            v[r][4*k+0] = f.x; v[r][4*k+1] = f.y;
            v[r][4*k+2] = f.z; v[r][4*k+3] = f.w;
        }
    }

    // ---- lane totals per row (4 independent chains, ILP=4) ----
    float tot[D];
    #pragma unroll
    for (int r = 0; r < D; ++r) {
        float s = 0.0f;
        #pragma unroll
        for (int k = 0; k < PER_LANE; ++k) s += v[r][k];
        tot[r] = s;
    }

    // ---- wave-level inclusive scan of lane totals, 4 rows interleaved ----
    float scan[D];
    #pragma unroll
    for (int r = 0; r < D; ++r) scan[r] = tot[r];
    #pragma unroll
    for (int off = 1; off < 64; off <<= 1) {
        #pragma unroll
        for (int r = 0; r < D; ++r) {
            float up = __shfl_up(scan[r], off, 64);
            if (lane >= off) scan[r] += up;
        }
    }

    // ---- Tend = min over rows of full-row sum (lane 63's inclusive scan) --
    float tend = __shfl(scan[0], 63, 64);
    #pragma unroll
    for (int r = 1; r < D; ++r) tend = fminf(tend, __shfl(scan[r], 63, 64));

    // ---- walk the 32 columns: running prefixes, min/max across rows ----
    float run[D];
    #pragma unroll
    for (int r = 0; r < D; ++r) run[r] = scan[r] - tot[r];  // exclusive prefix

    float acc = 0.0f;
    #pragma unroll
    for (int k = 0; k < PER_LANE; ++k) {
        #pragma unroll
        for (int r = 0; r < D; ++r) run[r] += v[r][k];
        float a01 = fminf(run[0], run[1]), a23 = fminf(run[2], run[3]);
        float b01 = fmaxf(run[0], run[1]), b23 = fmaxf(run[2], run[3]);
        float a = fminf(a01, a23);
        float b = fmaxf(b01, b23);
        acc += (tend - a) - fmaxf(0.0f, tend - b);
    }

    // ---- wave reduction of acc ----
    #pragma unroll
    for (int off = 32; off > 0; off >>= 1)
        acc += __shfl_down(acc, off, 64);
    if (lane == 0) out[0] = acc;
}

extern "C" void kernel_launch(void* const* d_in, const int* in_sizes, int n_in,
                              void* d_out, int out_size, void* d_ws, size_t ws_size,
                              hipStream_t stream) {
    (void)in_sizes; (void)n_in; (void)d_ws; (void)ws_size; (void)out_size;
    const float* x = (const float*)d_in[0];
    float* out = (float*)d_out;
    demd_kernel<<<1, 64, 0, stream>>>(x, out);
}